// Round 3
// baseline (122.581 us; speedup 1.0000x reference)
//
#include <hip/hip_runtime.h>

// knnLoss: B=4, downsample 400x400 stride-4 -> 10000 pts x 3ch, NN sq-dist mean.
// d2(t,s) = tt + (ss - 2 t.s); min over the paren term, add tt at the end.
// Sources pre-transformed to float4(-2x,-2y,-2z,ss): 3 fma + 0.5 min3 per pair.
//
// knn config: BLOCK=64 (1 wave), TPT=8 targets/thread -> ds_read_b128 count
// = 1 per source per wave, amortized over 512 pairs/group; grid 20x16x4=1280
// blocks = exactly 5/CU (even). LDS reads software-pipelined one group ahead.

#define BATCH  4
#define NPTS   10000
#define NPAD   10240      // padded target count per batch
#define H      400
#define W      400
#define STRIDE 4
#define OUTW   100
#define NC     16         // source chunks
#define CHUNK  625        // NPTS / NC
#define CPAD   628        // chunk padded to multiple of 4 with sentinels
#define KBLOCK 64         // knn block = 1 wave
#define TPT    8          // targets per thread
#define TBLKS  20         // NPAD / (KBLOCK*TPT)
#define RBLOCK 256        // prep/reduce block

__device__ __forceinline__ float min3f(float a, float b, float c) {
    float r;
    asm("v_min3_f32 %0, %1, %2, %3" : "=v"(r) : "v"(a), "v"(b), "v"(c));
    return r;
}

// ---------------------------------------------------------------- kernel 1
__global__ void prep_kernel(const float* __restrict__ tgt,
                            const float* __restrict__ src,
                            float4* __restrict__ S4,
                            float4* __restrict__ T4) {
    int gid = blockIdx.x * blockDim.x + threadIdx.x;
    if (gid < BATCH * NPAD) {
        int b = gid / NPAD;
        int n = gid % NPAD;
        float4 v = make_float4(0.f, 0.f, 0.f, 0.f);
        if (n < NPTS) {
            int h = n / OUTW, w = n % OUTW;
            int base = ((b * 3) * H + h * STRIDE) * W + w * STRIDE;
            float x = tgt[base];
            float y = tgt[base + H * W];
            float z = tgt[base + 2 * H * W];
            v = make_float4(x, y, z, x * x + y * y + z * z);
        }
        T4[gid] = v;
    } else {
        int sid = gid - BATCH * NPAD;
        if (sid < BATCH * NPTS) {
            int b = sid / NPTS;
            int m = sid % NPTS;
            int h = m / OUTW, w = m % OUTW;
            int base = ((b * 3) * H + h * STRIDE) * W + w * STRIDE;
            float x = src[base];
            float y = src[base + H * W];
            float z = src[base + 2 * H * W];
            S4[sid] = make_float4(-2.f * x, -2.f * y, -2.f * z,
                                  x * x + y * y + z * z);
        }
    }
}

// ---------------------------------------------------------------- kernel 2
// block = (tblk, cblk, b): 512 targets x 625-source chunk, one wave.
#define COMPUTE4(q0, q1, q2, q3)                                   \
    _Pragma("unroll")                                              \
    for (int k = 0; k < TPT; k++) {                                \
        float d0 = fmaf(tx[k], q0.x, q0.w);                        \
        d0 = fmaf(ty[k], q0.y, d0);                                \
        d0 = fmaf(tz[k], q0.z, d0);                                \
        float d1 = fmaf(tx[k], q1.x, q1.w);                        \
        d1 = fmaf(ty[k], q1.y, d1);                                \
        d1 = fmaf(tz[k], q1.z, d1);                                \
        float d2 = fmaf(tx[k], q2.x, q2.w);                        \
        d2 = fmaf(ty[k], q2.y, d2);                                \
        d2 = fmaf(tz[k], q2.z, d2);                                \
        float d3 = fmaf(tx[k], q3.x, q3.w);                        \
        d3 = fmaf(ty[k], q3.y, d3);                                \
        d3 = fmaf(tz[k], q3.z, d3);                                \
        mn[k] = min3f(mn[k], min3f(d0, d1, d2), d3);               \
    }

__global__ __launch_bounds__(KBLOCK) void knn_kernel(
        const float4* __restrict__ S4,
        const float4* __restrict__ T4,
        float* __restrict__ M2) {
    __shared__ float4 lds[CPAD];
    const int tblk = blockIdx.x;  // 0..TBLKS-1
    const int cblk = blockIdx.y;  // 0..NC-1
    const int b    = blockIdx.z;  // 0..BATCH-1
    const int tid  = threadIdx.x; // 0..63

    const float4* sbase = S4 + b * NPTS + cblk * CHUNK;
    for (int i = tid; i < CHUNK; i += KBLOCK) lds[i] = sbase[i];
    if (tid < CPAD - CHUNK) lds[CHUNK + tid] = make_float4(0.f, 0.f, 0.f, 3.0e38f);

    const int tbase = b * NPAD + tblk * (KBLOCK * TPT) + tid;
    float tx[TPT], ty[TPT], tz[TPT], mn[TPT];
#pragma unroll
    for (int k = 0; k < TPT; k++) {
        float4 t = T4[tbase + k * KBLOCK];
        tx[k] = t.x; ty[k] = t.y; tz[k] = t.z;
        mn[k] = 3.0e38f;
    }
    __syncthreads();

    // software pipeline: group of 4 sources in flight one step ahead
    float4 c0 = lds[0], c1 = lds[1], c2 = lds[2], c3 = lds[3];
    for (int j = 4; j < CPAD; j += 4) {
        float4 n0 = lds[j + 0];
        float4 n1 = lds[j + 1];
        float4 n2 = lds[j + 2];
        float4 n3 = lds[j + 3];
        COMPUTE4(c0, c1, c2, c3)
        c0 = n0; c1 = n1; c2 = n2; c3 = n3;
    }
    COMPUTE4(c0, c1, c2, c3)

    float* obase = M2 + (cblk * BATCH + b) * NPAD + tblk * (KBLOCK * TPT) + tid;
#pragma unroll
    for (int k = 0; k < TPT; k++) obase[k * KBLOCK] = mn[k];
}

// ---------------------------------------------------------------- kernel 3
__global__ void reduce_kernel(const float* __restrict__ M2,
                              const float4* __restrict__ T4,
                              float* __restrict__ out) {
    __shared__ float red[RBLOCK / 64];
    int gid = blockIdx.x * RBLOCK + threadIdx.x;
    float val = 0.f;
    if (gid < BATCH * NPTS) {
        int b = gid / NPTS;
        int n = gid % NPTS;
        float m = 3.0e38f;
#pragma unroll
        for (int c = 0; c < NC; c++)
            m = fminf(m, M2[(c * BATCH + b) * NPAD + n]);
        float tt = T4[b * NPAD + n].w;
        val = fmaxf(m + tt, 0.f);
    }
#pragma unroll
    for (int off = 32; off > 0; off >>= 1)
        val += __shfl_down(val, off, 64);
    int lane = threadIdx.x & 63;
    int wave = threadIdx.x >> 6;
    if (lane == 0) red[wave] = val;
    __syncthreads();
    if (threadIdx.x == 0) {
        float s = 0.f;
        for (int wv = 0; wv < RBLOCK / 64; wv++) s += red[wv];
        atomicAdd(out, s * (1.0f / (BATCH * NPTS * 3)));
    }
}

extern "C" void kernel_launch(void* const* d_in, const int* in_sizes, int n_in,
                              void* d_out, int out_size, void* d_ws, size_t ws_size,
                              hipStream_t stream) {
    const float* tgt = (const float*)d_in[0];   // target_pc (4,3,400,400)
    const float* src = (const float*)d_in[1];   // source_pc (4,3,400,400)
    float* out = (float*)d_out;

    char* ws = (char*)d_ws;
    float4* S4 = (float4*)ws;                                   // B*NPTS float4
    float4* T4 = (float4*)(ws + (size_t)BATCH * NPTS * 16);     // B*NPAD float4
    float*  M2 = (float*)(ws + (size_t)BATCH * NPTS * 16
                             + (size_t)BATCH * NPAD * 16);      // NC*B*NPAD floats

    hipMemsetAsync(out, 0, sizeof(float), stream);

    int nprep = BATCH * NPAD + BATCH * NPTS;
    prep_kernel<<<(nprep + RBLOCK - 1) / RBLOCK, RBLOCK, 0, stream>>>(tgt, src, S4, T4);

    knn_kernel<<<dim3(TBLKS, NC, BATCH), KBLOCK, 0, stream>>>(S4, T4, M2);

    reduce_kernel<<<(BATCH * NPTS + RBLOCK - 1) / RBLOCK, RBLOCK, 0, stream>>>(
        M2, T4, out);
}

// Round 4
// 104.920 us; speedup vs baseline: 1.1683x; 1.1683x over previous
//
#include <hip/hip_runtime.h>

// knnLoss: B=4, downsample 400x400 stride-4 -> 10000 pts x 3ch, NN sq-dist mean.
// d2(t,s) = tt + (ss - 2 t.s); min over the paren term, add tt at the end.
// Sources pre-transformed to float4(-2x,-2y,-2z,ss): 3 fma + 0.5 min3 per pair.
//
// knn grid: (TBLKS=10, NC=32, B=4) = 1280 blocks of 256 thr = exactly 5
// blocks/CU, 20 waves/CU. Total ds_read_b128 = TBLKS*B*NPTS = 400k (NC-
// independent) -> LDS pipe ~8 us << VALU floor ~18 us. NC only adds TLP.

#define BATCH  4
#define NPTS   10000
#define NPAD   10240      // padded target count per batch
#define H      400
#define W      400
#define STRIDE 4
#define OUTW   100
#define NC     32         // source chunks (pure parallelism knob)
#define CHUNK  313        // ceil(NPTS/NC); last chunk short, sentinel-padded
#define CPAD   316        // chunk padded to multiple of 4
#define BLOCK  256
#define TPT    4          // targets per thread
#define TBLKS  10         // NPAD / (BLOCK*TPT)
#define RBLOCK 256

__device__ __forceinline__ float min3f(float a, float b, float c) {
    float r;
    asm("v_min3_f32 %0, %1, %2, %3" : "=v"(r) : "v"(a), "v"(b), "v"(c));
    return r;
}

// ---------------------------------------------------------------- kernel 1
__global__ void prep_kernel(const float* __restrict__ tgt,
                            const float* __restrict__ src,
                            float4* __restrict__ S4,
                            float4* __restrict__ T4) {
    int gid = blockIdx.x * blockDim.x + threadIdx.x;
    if (gid < BATCH * NPAD) {
        int b = gid / NPAD;
        int n = gid % NPAD;
        float4 v = make_float4(0.f, 0.f, 0.f, 0.f);
        if (n < NPTS) {
            int h = n / OUTW, w = n % OUTW;
            int base = ((b * 3) * H + h * STRIDE) * W + w * STRIDE;
            float x = tgt[base];
            float y = tgt[base + H * W];
            float z = tgt[base + 2 * H * W];
            v = make_float4(x, y, z, x * x + y * y + z * z);
        }
        T4[gid] = v;
    } else {
        int sid = gid - BATCH * NPAD;
        if (sid < BATCH * NPTS) {
            int b = sid / NPTS;
            int m = sid % NPTS;
            int h = m / OUTW, w = m % OUTW;
            int base = ((b * 3) * H + h * STRIDE) * W + w * STRIDE;
            float x = src[base];
            float y = src[base + H * W];
            float z = src[base + 2 * H * W];
            S4[sid] = make_float4(-2.f * x, -2.f * y, -2.f * z,
                                  x * x + y * y + z * z);
        }
    }
}

// ---------------------------------------------------------------- kernel 2
#define COMPUTE4(q0, q1, q2, q3)                                   \
    _Pragma("unroll")                                              \
    for (int k = 0; k < TPT; k++) {                                \
        float d0 = fmaf(tx[k], q0.x, q0.w);                        \
        d0 = fmaf(ty[k], q0.y, d0);                                \
        d0 = fmaf(tz[k], q0.z, d0);                                \
        float d1 = fmaf(tx[k], q1.x, q1.w);                        \
        d1 = fmaf(ty[k], q1.y, d1);                                \
        d1 = fmaf(tz[k], q1.z, d1);                                \
        float d2 = fmaf(tx[k], q2.x, q2.w);                        \
        d2 = fmaf(ty[k], q2.y, d2);                                \
        d2 = fmaf(tz[k], q2.z, d2);                                \
        float d3 = fmaf(tx[k], q3.x, q3.w);                        \
        d3 = fmaf(ty[k], q3.y, d3);                                \
        d3 = fmaf(tz[k], q3.z, d3);                                \
        mn[k] = min3f(mn[k], min3f(d0, d1, d2), d3);               \
    }

__global__ __launch_bounds__(BLOCK) void knn_kernel(
        const float4* __restrict__ S4,
        const float4* __restrict__ T4,
        float* __restrict__ M2) {
    __shared__ float4 lds[CPAD];
    const int tblk = blockIdx.x;  // 0..TBLKS-1
    const int cblk = blockIdx.y;  // 0..NC-1
    const int b    = blockIdx.z;  // 0..BATCH-1
    const int tid  = threadIdx.x;

    const int s0    = cblk * CHUNK;
    const int valid = (NPTS - s0 < CHUNK) ? (NPTS - s0) : CHUNK;
    const float4* sbase = S4 + b * NPTS + s0;
    for (int i = tid; i < CPAD; i += BLOCK)
        lds[i] = (i < valid) ? sbase[i] : make_float4(0.f, 0.f, 0.f, 3.0e38f);

    const int tbase = b * NPAD + tblk * (BLOCK * TPT) + tid;
    float tx[TPT], ty[TPT], tz[TPT], mn[TPT];
#pragma unroll
    for (int k = 0; k < TPT; k++) {
        float4 t = T4[tbase + k * BLOCK];
        tx[k] = t.x; ty[k] = t.y; tz[k] = t.z;
        mn[k] = 3.0e38f;
    }
    __syncthreads();

    // software pipeline: group of 4 sources fetched one step ahead
    float4 c0 = lds[0], c1 = lds[1], c2 = lds[2], c3 = lds[3];
    for (int j = 4; j < CPAD; j += 4) {
        float4 n0 = lds[j + 0];
        float4 n1 = lds[j + 1];
        float4 n2 = lds[j + 2];
        float4 n3 = lds[j + 3];
        COMPUTE4(c0, c1, c2, c3)
        c0 = n0; c1 = n1; c2 = n2; c3 = n3;
    }
    COMPUTE4(c0, c1, c2, c3)

    float* obase = M2 + (cblk * BATCH + b) * NPAD + tblk * (BLOCK * TPT) + tid;
#pragma unroll
    for (int k = 0; k < TPT; k++) obase[k * BLOCK] = mn[k];
}

// ---------------------------------------------------------------- kernel 3
__global__ void reduce_kernel(const float* __restrict__ M2,
                              const float4* __restrict__ T4,
                              float* __restrict__ out) {
    __shared__ float red[RBLOCK / 64];
    int gid = blockIdx.x * RBLOCK + threadIdx.x;
    float val = 0.f;
    if (gid < BATCH * NPTS) {
        int b = gid / NPTS;
        int n = gid % NPTS;
        float m = 3.0e38f;
#pragma unroll
        for (int c = 0; c < NC; c++)
            m = fminf(m, M2[(c * BATCH + b) * NPAD + n]);
        float tt = T4[b * NPAD + n].w;
        val = fmaxf(m + tt, 0.f);
    }
#pragma unroll
    for (int off = 32; off > 0; off >>= 1)
        val += __shfl_down(val, off, 64);
    int lane = threadIdx.x & 63;
    int wave = threadIdx.x >> 6;
    if (lane == 0) red[wave] = val;
    __syncthreads();
    if (threadIdx.x == 0) {
        float s = 0.f;
        for (int wv = 0; wv < RBLOCK / 64; wv++) s += red[wv];
        atomicAdd(out, s * (1.0f / (BATCH * NPTS * 3)));
    }
}

extern "C" void kernel_launch(void* const* d_in, const int* in_sizes, int n_in,
                              void* d_out, int out_size, void* d_ws, size_t ws_size,
                              hipStream_t stream) {
    const float* tgt = (const float*)d_in[0];   // target_pc (4,3,400,400)
    const float* src = (const float*)d_in[1];   // source_pc (4,3,400,400)
    float* out = (float*)d_out;

    char* ws = (char*)d_ws;
    float4* S4 = (float4*)ws;                                   // B*NPTS float4
    float4* T4 = (float4*)(ws + (size_t)BATCH * NPTS * 16);     // B*NPAD float4
    float*  M2 = (float*)(ws + (size_t)BATCH * NPTS * 16
                             + (size_t)BATCH * NPAD * 16);      // NC*B*NPAD floats

    hipMemsetAsync(out, 0, sizeof(float), stream);

    int nprep = BATCH * NPAD + BATCH * NPTS;
    prep_kernel<<<(nprep + RBLOCK - 1) / RBLOCK, RBLOCK, 0, stream>>>(tgt, src, S4, T4);

    knn_kernel<<<dim3(TBLKS, NC, BATCH), BLOCK, 0, stream>>>(S4, T4, M2);

    reduce_kernel<<<(BATCH * NPTS + RBLOCK - 1) / RBLOCK, RBLOCK, 0, stream>>>(
        M2, T4, out);
}

// Round 5
// 99.765 us; speedup vs baseline: 1.2287x; 1.0517x over previous
//
#include <hip/hip_runtime.h>

// knnLoss: B=4, downsample 400x400 stride-4 -> 10000 pts x 3ch, NN sq-dist mean.
// d2(t,s) = tt + (ss - 2 t.s); min over the paren term, add tt at the end.
// Sources pre-transformed to (-2x,-2y,-2z,ss).
//
// Inner math is PACKED fp32: v_pk_fma_f32 computes d for a PAIR of sources
// (3 pk_fma), then one v_min3_f32 folds both into the running min:
//   2.0 VALU instr per (target,source) pair, vs 3.5 scalar.
// LDS holds the chunk SoA (SX/SY/SZ/SW) so one broadcast ds_read_b128 per
// component yields 4 sources = two aligned float2 pairs, and the pk_fma
// addend {w0,w1} falls directly out of the SW load (no repack movs).
// Grid: (TBLKS=10, NC=32, B=4) = 1280 blocks x 256 = exactly 5 blocks/CU.

#define BATCH  4
#define NPTS   10000
#define NPAD   10240      // padded target count per batch
#define H      400
#define W      400
#define STRIDE 4
#define OUTW   100
#define NC     32         // source chunks (parallelism knob)
#define CHUNK  313        // ceil(NPTS/NC)
#define CPAD   320        // chunk padded to multiple of 8 (2-group unroll)
#define BLOCK  256
#define TPT    4          // targets per thread
#define TBLKS  10         // NPAD / (BLOCK*TPT)
#define RBLOCK 256

typedef float float2v __attribute__((ext_vector_type(2)));

__device__ __forceinline__ float min3f(float a, float b, float c) {
    float r;
    asm("v_min3_f32 %0, %1, %2, %3" : "=v"(r) : "v"(a), "v"(b), "v"(c));
    return r;
}

__device__ __forceinline__ float2v pk_fma(float2v a, float2v b, float2v c) {
    float2v d;
    asm("v_pk_fma_f32 %0, %1, %2, %3" : "=v"(d) : "v"(a), "v"(b), "v"(c));
    return d;
}

// ---------------------------------------------------------------- kernel 1
__global__ void prep_kernel(const float* __restrict__ tgt,
                            const float* __restrict__ src,
                            float4* __restrict__ S4,
                            float4* __restrict__ T4) {
    int gid = blockIdx.x * blockDim.x + threadIdx.x;
    if (gid < BATCH * NPAD) {
        int b = gid / NPAD;
        int n = gid % NPAD;
        float4 v = make_float4(0.f, 0.f, 0.f, 0.f);
        if (n < NPTS) {
            int h = n / OUTW, w = n % OUTW;
            int base = ((b * 3) * H + h * STRIDE) * W + w * STRIDE;
            float x = tgt[base];
            float y = tgt[base + H * W];
            float z = tgt[base + 2 * H * W];
            v = make_float4(x, y, z, x * x + y * y + z * z);
        }
        T4[gid] = v;
    } else {
        int sid = gid - BATCH * NPAD;
        if (sid < BATCH * NPTS) {
            int b = sid / NPTS;
            int m = sid % NPTS;
            int h = m / OUTW, w = m % OUTW;
            int base = ((b * 3) * H + h * STRIDE) * W + w * STRIDE;
            float x = src[base];
            float y = src[base + H * W];
            float z = src[base + 2 * H * W];
            S4[sid] = make_float4(-2.f * x, -2.f * y, -2.f * z,
                                  x * x + y * y + z * z);
        }
    }
}

// ---------------------------------------------------------------- kernel 2
// One 4-source group: qx/qy/qz/qw are float4 component vectors (4 sources).
// Per target: 6 pk_fma + 2 min3 = 8 instr for 4 pairs.
#define COMPUTE_GROUP(qx, qy, qz, qw)                                       \
    _Pragma("unroll")                                                       \
    for (int k = 0; k < TPT; k++) {                                         \
        float2v d01 = pk_fma((float2v){qx.x, qx.y}, txp[k],                 \
                             (float2v){qw.x, qw.y});                        \
        d01 = pk_fma((float2v){qy.x, qy.y}, typ[k], d01);                   \
        d01 = pk_fma((float2v){qz.x, qz.y}, tzp[k], d01);                   \
        float2v d23 = pk_fma((float2v){qx.z, qx.w}, txp[k],                 \
                             (float2v){qw.z, qw.w});                        \
        d23 = pk_fma((float2v){qy.z, qy.w}, typ[k], d23);                   \
        d23 = pk_fma((float2v){qz.z, qz.w}, tzp[k], d23);                   \
        mn[k] = min3f(mn[k], min3f(d01.x, d01.y, d23.x), d23.y);            \
    }

__global__ __launch_bounds__(BLOCK) void knn_kernel(
        const float4* __restrict__ S4,
        const float4* __restrict__ T4,
        float* __restrict__ M2) {
    __shared__ float4 SX[CPAD / 4], SY[CPAD / 4], SZ[CPAD / 4], SW[CPAD / 4];
    const int tblk = blockIdx.x;  // 0..TBLKS-1
    const int cblk = blockIdx.y;  // 0..NC-1
    const int b    = blockIdx.z;  // 0..BATCH-1
    const int tid  = threadIdx.x;

    const int s0    = cblk * CHUNK;
    const int valid = (NPTS - s0 < CHUNK) ? (NPTS - s0) : CHUNK;
    const float4* sbase = S4 + b * NPTS + s0;
    for (int i = tid; i < CPAD; i += BLOCK) {
        float4 s = (i < valid) ? sbase[i]
                               : make_float4(0.f, 0.f, 0.f, 3.0e38f);
        ((float*)SX)[i] = s.x;
        ((float*)SY)[i] = s.y;
        ((float*)SZ)[i] = s.z;
        ((float*)SW)[i] = s.w;
    }

    const int tbase = b * NPAD + tblk * (BLOCK * TPT) + tid;
    float2v txp[TPT], typ[TPT], tzp[TPT];
    float mn[TPT];
#pragma unroll
    for (int k = 0; k < TPT; k++) {
        float4 t = T4[tbase + k * BLOCK];
        txp[k] = (float2v){t.x, t.x};
        typ[k] = (float2v){t.y, t.y};
        tzp[k] = (float2v){t.z, t.z};
        mn[k] = 3.0e38f;
    }
    __syncthreads();

    // 2-group ping-pong: loads of both groups issued before either compute.
    for (int g = 0; g < CPAD / 4; g += 2) {
        float4 ax = SX[g],     ay = SY[g],     az = SZ[g],     aw = SW[g];
        float4 bx = SX[g + 1], by = SY[g + 1], bz = SZ[g + 1], bw = SW[g + 1];
        COMPUTE_GROUP(ax, ay, az, aw)
        COMPUTE_GROUP(bx, by, bz, bw)
    }

    float* obase = M2 + (cblk * BATCH + b) * NPAD + tblk * (BLOCK * TPT) + tid;
#pragma unroll
    for (int k = 0; k < TPT; k++) obase[k * BLOCK] = mn[k];
}

// ---------------------------------------------------------------- kernel 3
__global__ void reduce_kernel(const float* __restrict__ M2,
                              const float4* __restrict__ T4,
                              float* __restrict__ out) {
    __shared__ float red[RBLOCK / 64];
    int gid = blockIdx.x * RBLOCK + threadIdx.x;
    float val = 0.f;
    if (gid < BATCH * NPTS) {
        int b = gid / NPTS;
        int n = gid % NPTS;
        float m = 3.0e38f;
#pragma unroll
        for (int c = 0; c < NC; c++)
            m = fminf(m, M2[(c * BATCH + b) * NPAD + n]);
        float tt = T4[b * NPAD + n].w;
        val = fmaxf(m + tt, 0.f);
    }
#pragma unroll
    for (int off = 32; off > 0; off >>= 1)
        val += __shfl_down(val, off, 64);
    int lane = threadIdx.x & 63;
    int wave = threadIdx.x >> 6;
    if (lane == 0) red[wave] = val;
    __syncthreads();
    if (threadIdx.x == 0) {
        float s = 0.f;
        for (int wv = 0; wv < RBLOCK / 64; wv++) s += red[wv];
        atomicAdd(out, s * (1.0f / (BATCH * NPTS * 3)));
    }
}

extern "C" void kernel_launch(void* const* d_in, const int* in_sizes, int n_in,
                              void* d_out, int out_size, void* d_ws, size_t ws_size,
                              hipStream_t stream) {
    const float* tgt = (const float*)d_in[0];   // target_pc (4,3,400,400)
    const float* src = (const float*)d_in[1];   // source_pc (4,3,400,400)
    float* out = (float*)d_out;

    char* ws = (char*)d_ws;
    float4* S4 = (float4*)ws;                                   // B*NPTS float4
    float4* T4 = (float4*)(ws + (size_t)BATCH * NPTS * 16);     // B*NPAD float4
    float*  M2 = (float*)(ws + (size_t)BATCH * NPTS * 16
                             + (size_t)BATCH * NPAD * 16);      // NC*B*NPAD floats

    hipMemsetAsync(out, 0, sizeof(float), stream);

    int nprep = BATCH * NPAD + BATCH * NPTS;
    prep_kernel<<<(nprep + RBLOCK - 1) / RBLOCK, RBLOCK, 0, stream>>>(tgt, src, S4, T4);

    knn_kernel<<<dim3(TBLKS, NC, BATCH), BLOCK, 0, stream>>>(S4, T4, M2);

    reduce_kernel<<<(BATCH * NPTS + RBLOCK - 1) / RBLOCK, RBLOCK, 0, stream>>>(
        M2, T4, out);
}